// Round 6
// baseline (173.314 us; speedup 1.0000x reference)
//
#include <hip/hip_runtime.h>
#include <hip/hip_fp16.h>

// SGConvolution: out = A @ (A @ x), A sparse COO (edge_row sorted).
// N=100000, E=1600000, D=64 (== wave width; lane d owns feature d).
//
// R5 -> R6: CSR row-ownership kept (no atomics / no memsets / 3 dispatches),
// but the wave's whole edge range [rp[0], rp[4]) is processed as ONE
// continuous double-buffered gather pipeline (16 fp16 gathers per chunk,
// prefetch chunk k+1 while folding chunk k). Row boundaries are scalar
// compares against rowptr — no per-row pipeline drain, no per-row padding
// (R5 padded every row to 16 gathers and drained per row; that lost the ILP
// the atomic removal should have paid for).

#define N_NODES 100000
#define N_EDGES 1600000
#define D_FEAT  64
#define ROWS    4                      // rows per wave; 100000/4 = 25000 waves

__device__ __forceinline__ float readlane_f(float x, int j) {
    return __uint_as_float(__builtin_amdgcn_readlane(__float_as_uint(x), j));
}

__device__ __forceinline__ void store_feat(__half* p, float v) { *p = __float2half_rn(v); }
__device__ __forceinline__ void store_feat(float*  p, float v) { *p = v; }

// Fused prep: x (fp32) -> h16 cast, plus rowptr[n] = lower_bound(erow, n).
__global__ __launch_bounds__(256) void prep_kernel(
    const float* __restrict__ x, __half* __restrict__ h16,
    const int* __restrict__ erow, int* __restrict__ rowptr)
{
    const int gid = blockIdx.x * blockDim.x + threadIdx.x;
    const int n4  = (N_NODES * D_FEAT) / 4;          // 1,600,000 cast threads
    if (gid < n4) {
        const float4 v = ((const float4*)x)[gid];
        ((__half2*)h16)[2 * gid]     = __floats2half2_rn(v.x, v.y);
        ((__half2*)h16)[2 * gid + 1] = __floats2half2_rn(v.z, v.w);
    } else {
        const int n = gid - n4;                      // 0..N_NODES inclusive
        if (n <= N_NODES) {
            int lo = 0, hi = N_EDGES;
            while (lo < hi) {
                const int mid = (lo + hi) >> 1;
                if (erow[mid] < n) lo = mid + 1; else hi = mid;
            }
            rowptr[n] = lo;
        }
    }
}

// CSR SpMM: wave w owns rows [4w, 4w+4). Continuous gather pipeline over the
// wave's whole edge range; scalar row-boundary flushes; each row stored once.
template <typename OutT>
__global__ __launch_bounds__(256) void sg_spmm_csr(
    const __half* __restrict__ h,        // [N, 64] fp16 feature table
    const int*    __restrict__ rowptr,   // [N+1]
    const int*    __restrict__ ecol,     // [E] source cols (grouped by row)
    const float*  __restrict__ eval,     // [E] edge weights
    OutT*         __restrict__ out)      // [N, 64] (fp16 round 1, fp32 round 2)
{
    const int lane = threadIdx.x & 63;
    const int wave = (int)((blockIdx.x * blockDim.x + threadIdx.x) >> 6);
    const int r0   = wave * ROWS;
    if (r0 >= N_NODES) return;

    // Wave-uniform row pointers -> SGPRs.
    const int rp0 = __builtin_amdgcn_readfirstlane(rowptr[r0 + 0]);
    const int rp1 = __builtin_amdgcn_readfirstlane(rowptr[r0 + 1]);
    const int rp2 = __builtin_amdgcn_readfirstlane(rowptr[r0 + 2]);
    const int rp3 = __builtin_amdgcn_readfirstlane(rowptr[r0 + 3]);
    const int rp4 = __builtin_amdgcn_readfirstlane(rowptr[r0 + 4]);

    float acc = 0.0f;
    int   r   = 0;         // current owned-row index (scalar)
    int   bnd = rp1;       // first edge NOT in current row (scalar)

    for (int eb = rp0; eb < rp4; eb += 64) {
        const int n = min(64, rp4 - eb);           // real edges in this batch
        // Coalesced lane-preload of up to 64 edge (col, weight); pads are
        // col 0 / weight 0 -> gather of row 0 scaled by 0 (harmless).
        const int   c_v = (lane < n) ? ecol[eb + lane] : 0;
        const float w_v = (lane < n) ? eval[eb + lane] : 0.0f;

        __half g[2][16];
        // Issue chunk 0.
#pragma unroll
        for (int j = 0; j < 16; ++j) {
            const int c = __builtin_amdgcn_readlane(c_v, j);
            g[0][j] = h[(size_t)c * D_FEAT + lane];
        }
#pragma unroll
        for (int k = 0; k < 4; ++k) {
            if (k * 16 < n) {
                if ((k + 1) * 16 < n) {
                    // Prefetch chunk k+1 while folding chunk k.
#pragma unroll
                    for (int j = 0; j < 16; ++j) {
                        const int c = __builtin_amdgcn_readlane(c_v, (k + 1) * 16 + j);
                        g[(k + 1) & 1][j] = h[(size_t)c * D_FEAT + lane];
                    }
                }
#pragma unroll
                for (int j = 0; j < 16; ++j) {
                    const int e = eb + k * 16 + j;   // scalar edge index
                    // Row advance: all real edges < e are folded, so any row
                    // with rp[r+1] <= e is complete (holds for pad e too).
                    while (r < ROWS && e >= bnd) {
                        store_feat(&out[(size_t)(r0 + r) * D_FEAT + lane], acc);
                        acc = 0.0f;
                        ++r;
                        bnd = (r == 1) ? rp2 : (r == 2) ? rp3 : rp4;
                    }
                    acc += readlane_f(w_v, k * 16 + j) * __half2float(g[k & 1][j]);
                }
            }
        }
    }
    // Flush current row and any trailing empty rows.
    while (r < ROWS) {
        store_feat(&out[(size_t)(r0 + r) * D_FEAT + lane], acc);
        acc = 0.0f;
        ++r;
    }
}

// Minimal fallback if ws is too small for the fp16 path (not expected).
__global__ __launch_bounds__(256) void spmm_atomic_f32(
    const float* __restrict__ h, const int* __restrict__ erow,
    const int* __restrict__ ecol, const float* __restrict__ eval,
    float* __restrict__ out)
{
    const int lane  = threadIdx.x & 63;
    const int wave  = (int)((blockIdx.x * blockDim.x + threadIdx.x) >> 6);
    const int start = wave * 64;
    if (start >= N_EDGES) return;
    int cur_row = erow[start];
    float acc = 0.0f;
    for (int e = start; e < start + 64; ++e) {
        const int r = erow[e];
        if (r != cur_row) {
            atomicAdd(&out[(size_t)cur_row * D_FEAT + lane], acc);
            acc = 0.0f; cur_row = r;
        }
        acc += eval[e] * h[(size_t)ecol[e] * D_FEAT + lane];
    }
    atomicAdd(&out[(size_t)cur_row * D_FEAT + lane], acc);
}

extern "C" void kernel_launch(void* const* d_in, const int* in_sizes, int n_in,
                              void* d_out, int out_size, void* d_ws, size_t ws_size,
                              hipStream_t stream) {
    const float* x    = (const float*)d_in[0];
    const int*   erow = (const int*)  d_in[1];
    const int*   ecol = (const int*)  d_in[2];
    const float* eval = (const float*)d_in[3];
    float*       out  = (float*)d_out;

    const size_t n_elem    = (size_t)N_NODES * D_FEAT;            // 6.4e6
    const size_t f16_bytes = n_elem * sizeof(__half);             // 12.8 MB
    const size_t off_a     = 1 << 20;                             // rowptr pad
    const size_t off_b     = off_a + f16_bytes;
    const size_t needed    = off_b + f16_bytes;                   // ~26.7 MB

    const int threads = 256;

    if (ws_size >= needed) {
        int*    rowptr = (int*)d_ws;
        __half* h16a   = (__half*)((char*)d_ws + off_a);          // cast(x)
        __half* h16b   = (__half*)((char*)d_ws + off_b);          // h1 in fp16

        const int prep_total  = (int)(n_elem / 4) + N_NODES + 1;  // 1,700,001
        const int prep_blocks = (prep_total + threads - 1) / threads;
        const int spmm_blocks = (N_NODES / ROWS) * 64 / threads;  // 6250 exactly

        prep_kernel<<<prep_blocks, threads, 0, stream>>>(x, h16a, erow, rowptr);
        sg_spmm_csr<__half><<<spmm_blocks, threads, 0, stream>>>(
            h16a, rowptr, ecol, eval, h16b);
        sg_spmm_csr<float><<<spmm_blocks, threads, 0, stream>>>(
            h16b, rowptr, ecol, eval, out);
    } else {
        // fp32 atomic fallback (ws only fits the fp32 intermediate)
        float* h1 = (float*)d_ws;
        const size_t f32_bytes = n_elem * sizeof(float);
        hipMemsetAsync(h1, 0, f32_bytes, stream);
        hipMemsetAsync(out, 0, f32_bytes, stream);
        const int blocks = (N_EDGES / 64) * 64 / threads;
        spmm_atomic_f32<<<blocks, threads, 0, stream>>>(x, erow, ecol, eval, h1);
        spmm_atomic_f32<<<blocks, threads, 0, stream>>>(h1, erow, ecol, eval, out);
    }
}

// Round 7
// 171.578 us; speedup vs baseline: 1.0101x; 1.0101x over previous
//
#include <hip/hip_runtime.h>
#include <hip/hip_fp16.h>

// SGConvolution: out = A @ (A @ x), A sparse COO (edge_row sorted).
// N=100000, E=1600000, D=64 (== wave width).
//
// R6 -> R7: PAIR GATHERS. R4/R5/R6 all issue 1 VMEM per edge and all land at
// ~43 us/spmm -> hypothesis: per-VMEM-instruction cost is the floor. Now one
// wave64 global_load_dword (__half2) covers TWO edges' feature rows:
//   lanes 0-31  : row col(e0), lane i -> features {2i, 2i+1}
//   lanes 32-63 : row col(e1), lane i-32 -> features {2(i-32), 2(i-32)+1}
// Accumulator is per-lane float2, split across half-waves; row flush combines
// halves with shfl_xor(32) and lanes 0-31 store the 64 features. A row
// boundary splitting a pair is handled by half-wave w-masking (scalar branch,
// ~1 in 8 pairs). Cross-batch edge-data prefetch added.

#define N_NODES 100000
#define N_EDGES 1600000
#define D_FEAT  64
#define ROWS    4                      // rows per wave; 100000/4 = 25000 waves

__device__ __forceinline__ float readlane_f(float x, int j) {
    return __uint_as_float(__builtin_amdgcn_readlane(__float_as_uint(x), j));
}

__device__ __forceinline__ void store_pair(__half* row, int j, float x, float y) {
    ((__half2*)row)[j] = __floats2half2_rn(x, y);
}
__device__ __forceinline__ void store_pair(float* row, int j, float x, float y) {
    float2 v; v.x = x; v.y = y;
    ((float2*)row)[j] = v;
}

// Fused prep: x (fp32) -> h16 cast, plus rowptr[n] = lower_bound(erow, n).
__global__ __launch_bounds__(256) void prep_kernel(
    const float* __restrict__ x, __half* __restrict__ h16,
    const int* __restrict__ erow, int* __restrict__ rowptr)
{
    const int gid = blockIdx.x * blockDim.x + threadIdx.x;
    const int n4  = (N_NODES * D_FEAT) / 4;          // 1,600,000 cast threads
    if (gid < n4) {
        const float4 v = ((const float4*)x)[gid];
        ((__half2*)h16)[2 * gid]     = __floats2half2_rn(v.x, v.y);
        ((__half2*)h16)[2 * gid + 1] = __floats2half2_rn(v.z, v.w);
    } else {
        const int n = gid - n4;                      // 0..N_NODES inclusive
        if (n <= N_NODES) {
            int lo = 0, hi = N_EDGES;
            while (lo < hi) {
                const int mid = (lo + hi) >> 1;
                if (erow[mid] < n) lo = mid + 1; else hi = mid;
            }
            rowptr[n] = lo;
        }
    }
}

// CSR SpMM, pair-gather version. Wave w owns rows [4w, 4w+4).
template <typename OutT>
__global__ __launch_bounds__(256) void sg_spmm_csr(
    const __half* __restrict__ h,        // [N, 64] fp16 feature table
    const int*    __restrict__ rowptr,   // [N+1]
    const int*    __restrict__ ecol,     // [E] source cols (grouped by row)
    const float*  __restrict__ eval,     // [E] edge weights
    OutT*         __restrict__ out)      // [N, 64] (fp16 round 1, fp32 round 2)
{
    const int  lane   = threadIdx.x & 63;
    const int  lane31 = lane & 31;
    const bool hi     = lane >= 32;
    const int  wave   = (int)((blockIdx.x * blockDim.x + threadIdx.x) >> 6);
    const int  r0     = wave * ROWS;
    if (r0 >= N_NODES) return;

    const int rp0 = __builtin_amdgcn_readfirstlane(rowptr[r0 + 0]);
    const int rp1 = __builtin_amdgcn_readfirstlane(rowptr[r0 + 1]);
    const int rp2 = __builtin_amdgcn_readfirstlane(rowptr[r0 + 2]);
    const int rp3 = __builtin_amdgcn_readfirstlane(rowptr[r0 + 3]);
    const int rp4 = __builtin_amdgcn_readfirstlane(rowptr[r0 + 4]);

    float accx = 0.0f, accy = 0.0f;
    int   r    = 0;          // current owned-row index (scalar)
    int   bnd  = rp1;        // first edge NOT in current row (scalar)

#define FLUSH_ROW()                                                         \
    do {                                                                    \
        float tx = accx + __shfl_xor(accx, 32, 64);                         \
        float ty = accy + __shfl_xor(accy, 32, 64);                         \
        if (!hi) store_pair(out + (size_t)(r0 + r) * D_FEAT, lane31, tx, ty);\
        accx = 0.0f; accy = 0.0f;                                           \
        ++r;                                                                \
        bnd = (r == 1) ? rp2 : (r == 2) ? rp3 : rp4;                        \
    } while (0)

    // Preload first batch's 64 edge triples (lane i = edge rp0+i; pads w=0,c=0).
    int cv = 0; float wv = 0.0f;
    if (rp0 < rp4) {
        const int n0 = rp4 - rp0;
        cv = (lane < n0) ? ecol[rp0 + lane] : 0;
        wv = (lane < n0) ? eval[rp0 + lane] : 0.0f;
    }

    for (int eb = rp0; eb < rp4; eb += 64) {
        const int n = min(64, rp4 - eb);

        // Prefetch next batch's edge data (independent -> overlaps the fold).
        int cvn = 0; float wvn = 0.0f;
        if (eb + 64 < rp4) {
            const int nn = min(64, rp4 - (eb + 64));
            cvn = (lane < nn) ? ecol[eb + 64 + lane] : 0;
            wvn = (lane < nn) ? eval[eb + 64 + lane] : 0.0f;
        }

        // 32 pairs per batch; chunks of 8 pairs, double-buffered gathers.
        __half2 g[2][8];
#pragma unroll
        for (int j = 0; j < 8; ++j) {                       // issue chunk 0
            const int c0  = __builtin_amdgcn_readlane(cv, 2 * j);
            const int c1  = __builtin_amdgcn_readlane(cv, 2 * j + 1);
            const int col = hi ? c1 : c0;
            g[0][j] = ((const __half2*)(h + (size_t)col * D_FEAT))[lane31];
        }
#pragma unroll
        for (int k = 0; k < 4; ++k) {
            if (k * 16 < n) {
                if ((k + 1) * 16 < n) {                     // prefetch chunk k+1
#pragma unroll
                    for (int j = 0; j < 8; ++j) {
                        const int p   = (k + 1) * 8 + j;
                        const int c0  = __builtin_amdgcn_readlane(cv, 2 * p);
                        const int c1  = __builtin_amdgcn_readlane(cv, 2 * p + 1);
                        const int col = hi ? c1 : c0;
                        g[(k + 1) & 1][j] = ((const __half2*)(h + (size_t)col * D_FEAT))[lane31];
                    }
                }
#pragma unroll
                for (int j = 0; j < 8; ++j) {               // fold chunk k
                    const int   p   = k * 8 + j;
                    const int   E0  = eb + 2 * p;           // scalar edge idx
                    const int   E1  = E0 + 1;
                    const float sw0 = readlane_f(wv, 2 * p);
                    const float sw1 = readlane_f(wv, 2 * p + 1);
                    const float2 f  = __half22float2(g[k & 1][j]);

                    while (r < ROWS && E0 >= bnd) FLUSH_ROW();
                    if (E1 >= bnd && r < ROWS) {
                        // boundary between e0 and e1: fold e0 (lo half) only
                        const float wl = hi ? 0.0f : sw0;
                        accx += wl * f.x; accy += wl * f.y;
                        while (r < ROWS && E1 >= bnd) FLUSH_ROW();
                        const float wh = hi ? sw1 : 0.0f;   // fold e1 (hi half)
                        accx += wh * f.x; accy += wh * f.y;
                    } else {
                        const float ws = hi ? sw1 : sw0;    // pads: w==0
                        accx += ws * f.x; accy += ws * f.y;
                    }
                }
            }
        }
        cv = cvn; wv = wvn;
    }
    while (r < ROWS) FLUSH_ROW();                           // incl. empty rows
#undef FLUSH_ROW
}

// Minimal fallback if ws is too small for the fp16 path (not expected).
__global__ __launch_bounds__(256) void spmm_atomic_f32(
    const float* __restrict__ h, const int* __restrict__ erow,
    const int* __restrict__ ecol, const float* __restrict__ eval,
    float* __restrict__ out)
{
    const int lane  = threadIdx.x & 63;
    const int wave  = (int)((blockIdx.x * blockDim.x + threadIdx.x) >> 6);
    const int start = wave * 64;
    if (start >= N_EDGES) return;
    int cur_row = erow[start];
    float acc = 0.0f;
    for (int e = start; e < start + 64; ++e) {
        const int r = erow[e];
        if (r != cur_row) {
            atomicAdd(&out[(size_t)cur_row * D_FEAT + lane], acc);
            acc = 0.0f; cur_row = r;
        }
        acc += eval[e] * h[(size_t)ecol[e] * D_FEAT + lane];
    }
    atomicAdd(&out[(size_t)cur_row * D_FEAT + lane], acc);
}

extern "C" void kernel_launch(void* const* d_in, const int* in_sizes, int n_in,
                              void* d_out, int out_size, void* d_ws, size_t ws_size,
                              hipStream_t stream) {
    const float* x    = (const float*)d_in[0];
    const int*   erow = (const int*)  d_in[1];
    const int*   ecol = (const int*)  d_in[2];
    const float* eval = (const float*)d_in[3];
    float*       out  = (float*)d_out;

    const size_t n_elem    = (size_t)N_NODES * D_FEAT;            // 6.4e6
    const size_t f16_bytes = n_elem * sizeof(__half);             // 12.8 MB
    const size_t off_a     = 1 << 20;                             // rowptr pad
    const size_t off_b     = off_a + f16_bytes;
    const size_t needed    = off_b + f16_bytes;                   // ~26.7 MB

    const int threads = 256;

    if (ws_size >= needed) {
        int*    rowptr = (int*)d_ws;
        __half* h16a   = (__half*)((char*)d_ws + off_a);          // cast(x)
        __half* h16b   = (__half*)((char*)d_ws + off_b);          // h1 in fp16

        const int prep_total  = (int)(n_elem / 4) + N_NODES + 1;  // 1,700,001
        const int prep_blocks = (prep_total + threads - 1) / threads;
        const int spmm_blocks = (N_NODES / ROWS) * 64 / threads;  // 6250 exactly

        prep_kernel<<<prep_blocks, threads, 0, stream>>>(x, h16a, erow, rowptr);
        sg_spmm_csr<__half><<<spmm_blocks, threads, 0, stream>>>(
            h16a, rowptr, ecol, eval, h16b);
        sg_spmm_csr<float><<<spmm_blocks, threads, 0, stream>>>(
            h16b, rowptr, ecol, eval, out);
    } else {
        // fp32 atomic fallback (ws only fits the fp32 intermediate)
        float* h1 = (float*)d_ws;
        const size_t f32_bytes = n_elem * sizeof(float);
        hipMemsetAsync(h1, 0, f32_bytes, stream);
        hipMemsetAsync(out, 0, f32_bytes, stream);
        const int blocks = (N_EDGES / 64) * 64 / threads;
        spmm_atomic_f32<<<blocks, threads, 0, stream>>>(x, erow, ecol, eval, h1);
        spmm_atomic_f32<<<blocks, threads, 0, stream>>>(h1, erow, ecol, eval, out);
    }
}